// Round 11
// baseline (51.925 us; speedup 1.0000x reference)
//
#include <hip/hip_runtime.h>

// PixelEffectModule: 8-bin intensity histogram over 11x11 windows at stride 8,
// argmax bin, output that bin's mean RGB, upsampled 8x8.
// Input: rgb (1,3,2048,2048) fp32 in [0,255). Output: (1,3,2048,2048) fp32.
//
// R11 = R10's verified skeleton (parts=8 half-wave, XCD swizzle, masks,
// packed-u64 counts, nibble cache, argmax, shfl(32)+LDS reduces, row writes;
// absmax 0.0) + forced-MLP single-load structure:
//  - all 24 float4 row loads issued up front and PINNED via empty asm
//    ("+v" operands): compiler must issue the full burst (24 KB in flight
//    per wave) and cannot re-sink loads (R10: VGPR=36 proved sinking).
//  - data stays pinned across the argmax barrier; pass 2 reads REGISTERS
//    (zero reloads, second latency exposure eliminated). R5's version of
//    this failed only because its count reduce used shfl_xor(1)/(2) over
//    cell-lanes (summed neighboring cells); R10's shfl_xor(32) is correct.
//  - __launch_bounds__(256,4): 128-VGPR budget for ~118 live; spill
//    tripwire = WRITE_SIZE > 60 MB (R6-R8 signature).

#define Wd 2048
#define HW (2048 * 2048)

typedef unsigned int u32;
typedef unsigned long long u64;
typedef float f32x4 __attribute__((ext_vector_type(4)));

// correctly-rounded t/3 (Markstein), 3 ops vs ~9-inst div expansion
__device__ __forceinline__ float div3(float t) {
    const float c = 0x1.555556p-2f;  // RN(1/3)
    float q0 = t * c;
    float r  = __builtin_fmaf(q0, -3.0f, t);
    return __builtin_fmaf(r, c, q0);
}

// keep 12 float4s materialized in VGPRs at this point (no sink, no remat)
#define PIN12(A, B, C)                                                        \
    asm volatile("" : "+v"((A)[0]), "+v"((A)[1]), "+v"((A)[2]), "+v"((A)[3]), \
                      "+v"((B)[0]), "+v"((B)[1]), "+v"((B)[2]), "+v"((B)[3]), \
                      "+v"((C)[0]), "+v"((C)[1]), "+v"((C)[2]), "+v"((C)[3]))

__global__ __launch_bounds__(256, 4)
void pixel_effect_kernel(const float* __restrict__ rgb, float* __restrict__ out) {
    const int w    = threadIdx.x >> 6;         // wave 0..3
    const int half = (threadIdx.x >> 5) & 1;   // half-wave
    const int cl   = threadIdx.x & 31;         // cell within 32-strip
    const int p    = 2 * w + half;             // row-band part 0..7

    // XCD swizzle (grid 2048 = 8*256, bijective): XCD (wgid&7) owns slots
    // [256*xcd, 256*xcd+256) = 32 contiguous cell-rows.
    u32 wgid = blockIdx.x;
    u32 slot = (wgid & 7u) * 256u + (wgid >> 3);
    const int oy  = (int)(slot >> 3);
    const int bx8 = (int)(slot & 7u);
    const int ox  = bx8 * 32 + cl;

    const float* Rp = rgb;
    const float* Gp = rgb + HW;
    const float* Bp = rgb + 2 * HW;

    // slot j maps x = xbase + j. Interior: xbase=8*(ox-1), valid j in [3,13].
    // ox==0: xbase=0, valid j in [0,5]. All 4 quads always in bounds.
    const int xbase = (ox == 0) ? 0 : ox * 8 - 8;
    const u32 vmask = (ox == 0) ? 0x003Fu : 0x3FF8u;
    const int ytop  = oy * 8 - 5;
    const int rs = (p < 3) ? 2 * p : (3 + p);  // first window-row of this part
    const int nr = (p < 3) ? 2 : 1;            // rows: 2,2,2,1,1,1,1,1

    f32x4 vr[2][4], vg[2][4], vb[2][4];        // live across the barrier
    bool  act[2];

    // ---- load phase: up to 24 dwordx4 issued back-to-back, then pinned ----
#pragma unroll
    for (int k = 0; k < 2; ++k) {
        int y = ytop + rs + k;                 // uniform per half-wave
        act[k] = (k < nr) && (y >= 0);
        if (act[k]) {
            int off = y * Wd + xbase;
#pragma unroll
            for (int q = 0; q < 4; ++q) {
                vr[k][q] = *(const f32x4*)(Rp + off + 4 * q);
                vg[k][q] = *(const f32x4*)(Gp + off + 4 * q);
                vb[k][q] = *(const f32x4*)(Bp + off + 4 * q);
            }
            PIN12(vr[k], vg[k], vb[k]);
        }
    }

    // ---- bin phase: packed byte counts + per-px nibble cache ----
    u64 c64 = 0;
    u32 nbl[2], nbh[2];
#pragma unroll
    for (int k = 0; k < 2; ++k) {
        nbl[k] = 0xFFFFFFFFu; nbh[k] = 0xFFFFFFFFu;
        if (act[k]) {
            u32 bl = 0, bh = 0;
#pragma unroll
            for (int j = 0; j < 14; ++j) {
                float m = div3(vr[k][j >> 2][j & 3] + vg[k][j >> 2][j & 3]
                               + vb[k][j >> 2][j & 3]);
                u32 bin = (u32)(m * 0.03125f);     // trunc(mean/32), exact
                u32 valid = (vmask >> j) & 1u;
                c64 += (u64)valid << (bin << 3);
                u32 binv = valid ? bin : 15u;      // 15 matches no bin
                if (j < 8) bl |= binv << (4 * j);
                else       bh |= binv << (4 * (j - 8));
            }
            nbl[k] = bl; nbh[k] = bh;
        }
    }

    // ---- cross-half reduce (parts 2w, 2w+1), then 4-wave LDS reduce ----
    c64 += __shfl_xor(c64, 32);

    __shared__ u64 sc[4][32];
    if (half == 0) sc[w][cl] = c64;
    __syncthreads();

    u64 tot = sc[0][cl] + sc[1][cl] + sc[2][cl] + sc[3][cl];   // bytes <=121
    u32 lo = (u32)tot, hi = (u32)(tot >> 32);
    u32 best = 0, bc = lo & 0xFFu;
#pragma unroll
    for (int b = 1; b < 8; ++b) {
        u32 cb = ((b < 4 ? lo : hi) >> ((b & 3) * 8)) & 0xFFu;
        bool t = cb > bc;
        bc   = t ? cb : bc;
        best = t ? (u32)b : best;
    }

    // ---- selective sum straight from the pinned registers (no reloads) ----
    float sr = 0.f, sg = 0.f, sb = 0.f;
#pragma unroll
    for (int k = 0; k < 2; ++k) {
        if (act[k]) {
            PIN12(vr[k], vg[k], vb[k]);        // must still be in regs here
            u32 bl = nbl[k], bh = nbh[k];
#pragma unroll
            for (int j = 0; j < 14; ++j) {
                u32 bin = ((j < 8) ? (bl >> (4 * j))
                                   : (bh >> (4 * (j - 8)))) & 0xFu;
                float hm = (bin == best) ? 1.0f : 0.0f;
                sr = __builtin_fmaf(hm, vr[k][j >> 2][j & 3], sr);
                sg = __builtin_fmaf(hm, vg[k][j >> 2][j & 3], sg);
                sb = __builtin_fmaf(hm, vb[k][j >> 2][j & 3], sb);
            }
        }
    }
    sr += __shfl_xor(sr, 32);
    sg += __shfl_xor(sg, 32);
    sb += __shfl_xor(sb, 32);

    __shared__ float4 ss[4][32];
    if (half == 0) ss[w][cl] = make_float4(sr, sg, sb, 0.f);
    __syncthreads();

    float4 s0 = ss[0][cl], s1 = ss[1][cl], s2 = ss[2][cl], s3 = ss[3][cl];
    float fbc = (float)bc;
    float orv = (s0.x + s1.x + s2.x + s3.x) / fbc;
    float ogv = (s0.y + s1.y + s2.y + s3.y) / fbc;
    float obv = (s0.z + s1.z + s2.z + s3.z) / fbc;

    // ---- write: part p owns row p of the 8x8 block, 2x float4 per channel ----
    size_t base = (size_t)(oy * 8 + p) * Wd + (size_t)(ox * 8);
    float vals[3] = { orv, ogv, obv };
#pragma unroll
    for (int c = 0; c < 3; ++c) {
        float v = vals[c];
        float4 vv = make_float4(v, v, v, v);
        float* o = out + (size_t)c * HW + base;
        ((float4*)o)[0] = vv;
        ((float4*)o)[1] = vv;
    }
}

extern "C" void kernel_launch(void* const* d_in, const int* in_sizes, int n_in,
                              void* d_out, int out_size, void* d_ws, size_t ws_size,
                              hipStream_t stream) {
    const float* rgb = (const float*)d_in[0];
    float* out = (float*)d_out;
    dim3 block(256, 1, 1);                // 4 waves; wave = 32 cells x 2 parts
    dim3 grid(2048, 1, 1);                // 8 strips/cell-row x 256 rows (swizzled)
    hipLaunchKernelGGL(pixel_effect_kernel, grid, block, 0, stream, rgb, out);
}

// Round 12
// 25.950 us; speedup vs baseline: 2.0010x; 2.0010x over previous
//
#include <hip/hip_runtime.h>

// PixelEffectModule: 8-bin intensity histogram over 11x11 windows at stride 8,
// argmax bin, output that bin's mean RGB, upsampled 8x8.
// Input: rgb (1,3,2048,2048) fp32 in [0,255). Output: (1,3,2048,2048) fp32.
//
// R12 = R10's green compute path (absmax 0.0: parts=8 half-wave skeleton,
// XCD swizzle, masks, packed-u64 counts, nibble cache, argmax, shfl(32)+LDS
// reduces, row writes) with input staged via global_load_lds DMA:
//  - R6-R11 lesson: allocator pins <=64 VGPR; register-held data spills
//    (WRITE inflation), register batches get re-sunk (no MLP). DMA holds
//    in-flight data in the LDS queue, not VGPRs.
//  - per WG: 2178 16B chunks (3ch x 11 rows x 66 chunks) staged by 9
//    global_load_lds/thread (1KB/wave-inst, coalesced); __syncthreads()
//    drains vmcnt; both passes then read LDS (ds_read_b128).
//  - bank fix per rule #21 (both-sides): LINEAR LDS dest, INVERSE-swizzled
//    global source, swizzled reads. swz(w)=w^(((w>>3)&3)<<1) on 16B chunks
//    (involution, stays within each 66-chunk row): stride-8-float lane
//    pattern drops from 8-way conflict to <=2-way (free). Each ds_read_b128
//    reads exactly one swizzle granule -> contiguity preserved.
//  - last DMA iter: lanes past 2178 clamp source to chunk 2177, land in
//    LDS pad (chunks 2178..2303) -- no divergence around the DMA.

#define Wd 2048
#define HW (2048 * 2048)

typedef unsigned int u32;
typedef unsigned long long u64;
typedef float f32x4 __attribute__((ext_vector_type(4)));

// correctly-rounded t/3 (Markstein), 3 ops vs ~9-inst div expansion
__device__ __forceinline__ float div3(float t) {
    const float c = 0x1.555556p-2f;  // RN(1/3)
    float q0 = t * c;
    float r  = __builtin_fmaf(q0, -3.0f, t);
    return __builtin_fmaf(r, c, q0);
}

// 16B-chunk bank swizzle within a 66-chunk row (involution; 64,65 fixed pts)
__device__ __forceinline__ u32 swz(u32 w) { return w ^ (((w >> 3) & 3u) << 1); }

__global__ __launch_bounds__(256, 4)
void pixel_effect_kernel(const float* __restrict__ rgb, float* __restrict__ out) {
    __shared__ float  ldsf[9216];     // 2304 chunks x 4 floats: [ch][row][66] + pad
    __shared__ u64    sc[4][32];
    __shared__ float4 ss[4][32];

    const int tid  = threadIdx.x;
    const int w    = tid >> 6;                 // wave 0..3
    const int lane = tid & 63;
    const int half = (tid >> 5) & 1;           // half-wave
    const int cl   = tid & 31;                 // cell within 32-strip
    const int p    = 2 * w + half;             // row-band part 0..7

    // XCD swizzle (grid 2048 = 8*256, bijective): XCD (wgid&7) owns
    // 32 contiguous cell-rows.
    u32 wgid = blockIdx.x;
    u32 slot = (wgid & 7u) * 256u + (wgid >> 3);
    const int oy  = (int)(slot >> 3);
    const int bx8 = (int)(slot & 7u);
    const int ox  = bx8 * 32 + cl;

    const int xstart = bx8 ? (bx8 * 256 - 8) : 0;   // 264-float span start
    const int ytop   = oy * 8 - 5;

    // ---- DMA stage: 2178 chunks global -> LDS, linear dest, pre-swz src ----
#pragma unroll
    for (int it = 0; it < 9; ++it) {
        u32 cbase = (u32)it * 256u + (u32)(tid & ~63); // wave-uniform
        u32 c = cbase + (u32)lane;
        c = c < 2177u ? c : 2177u;                     // clamp -> junk to pad
        u32 ch  = c / 726u;
        u32 rem = c - ch * 726u;
        u32 row = rem / 66u;
        u32 wph = rem - row * 66u;                     // physical chunk-in-row
        u32 wlog = swz(wph);                           // logical chunk to fetch
        int y = ytop + (int)row; y = y < 0 ? 0 : y;    // clamped rows unread
        const float* gsrc = rgb + (size_t)ch * HW + (size_t)y * Wd
                          + (size_t)(xstart + (int)(wlog * 4u));
        float* ldst = &ldsf[cbase * 4u];               // wave-uniform base
        __builtin_amdgcn_global_load_lds(
            (const __attribute__((address_space(1))) void*)gsrc,
            (__attribute__((address_space(3))) void*)ldst, 16, 0, 0);
    }
    __syncthreads();   // drains vmcnt(0) before barrier (compiler-enforced)

    // slot j maps x = lx_off + j (LDS-row-relative). Interior: j in [3,13];
    // ox==0: j in [0,5]. 16-float read [lx_off, lx_off+16) always in row.
    const int lx_off = (ox == 0) ? 0 : (8 * ox - 8 - xstart);  // mult of 8
    const int w0     = lx_off >> 2;                            // even chunk idx
    const u32 vmask  = (ox == 0) ? 0x003Fu : 0x3FF8u;
    const int rs = (p < 3) ? 2 * p : (3 + p);  // first window-row of this part
    const int nr = (p < 3) ? 2 : 1;            // rows: 2,2,2,1,1,1,1,1

#define LOADROW(dst, chn, rr)                                                  \
    {                                                                          \
        int rb_ = ((chn) * 11 + (rr)) * 66;                                    \
        *(f32x4*)((dst) + 0)  = *(const f32x4*)&ldsf[(u32)(rb_ + swz(w0+0))*4u];\
        *(f32x4*)((dst) + 4)  = *(const f32x4*)&ldsf[(u32)(rb_ + swz(w0+1))*4u];\
        *(f32x4*)((dst) + 8)  = *(const f32x4*)&ldsf[(u32)(rb_ + swz(w0+2))*4u];\
        *(f32x4*)((dst) + 12) = *(const f32x4*)&ldsf[(u32)(rb_ + swz(w0+3))*4u];\
    }

    // ---- pass 1: bin pixels, packed byte counts + nibble cache ----
    u64 c64 = 0;
    u32 nbl[2], nbh[2];
#pragma unroll
    for (int k = 0; k < 2; ++k) {
        nbl[k] = 0xFFFFFFFFu; nbh[k] = 0xFFFFFFFFu;
        int r = rs + k;
        int y = ytop + r;                      // uniform per half-wave
        if (k < nr && y >= 0) {
            float vR[16], vG[16], vB[16];
            LOADROW(vR, 0, r) LOADROW(vG, 1, r) LOADROW(vB, 2, r)
            u32 bl = 0, bh = 0;
#pragma unroll
            for (int j = 0; j < 14; ++j) {
                float m = div3(vR[j] + vG[j] + vB[j]);
                u32 bin = (u32)(m * 0.03125f);     // trunc(mean/32), exact
                u32 valid = (vmask >> j) & 1u;
                c64 += (u64)valid << (bin << 3);
                u32 binv = valid ? bin : 15u;      // 15 matches no bin
                if (j < 8) bl |= binv << (4 * j);
                else       bh |= binv << (4 * (j - 8));
            }
            nbl[k] = bl; nbh[k] = bh;
        }
    }

    // ---- cross-half reduce (parts 2w, 2w+1), then 4-wave LDS reduce ----
    c64 += __shfl_xor(c64, 32);
    if (half == 0) sc[w][cl] = c64;
    __syncthreads();

    u64 tot = sc[0][cl] + sc[1][cl] + sc[2][cl] + sc[3][cl];   // bytes <=121
    u32 lo = (u32)tot, hi = (u32)(tot >> 32);
    u32 best = 0, bc = lo & 0xFFu;
#pragma unroll
    for (int b = 1; b < 8; ++b) {
        u32 cb = ((b < 4 ? lo : hi) >> ((b & 3) * 8)) & 0xFFu;
        bool t = cb > bc;
        bc   = t ? cb : bc;
        best = t ? (u32)b : best;
    }

    // ---- pass 2: re-read LDS (cheap), sum winning bin via nibbles ----
    float sr = 0.f, sg = 0.f, sb = 0.f;
#pragma unroll
    for (int k = 0; k < 2; ++k) {
        int r = rs + k;
        int y = ytop + r;
        if (k < nr && y >= 0) {
            float vR[16], vG[16], vB[16];
            LOADROW(vR, 0, r) LOADROW(vG, 1, r) LOADROW(vB, 2, r)
            u32 bl = nbl[k], bh = nbh[k];
#pragma unroll
            for (int j = 0; j < 14; ++j) {
                u32 bin = ((j < 8) ? (bl >> (4 * j))
                                   : (bh >> (4 * (j - 8)))) & 0xFu;
                float hm = (bin == best) ? 1.0f : 0.0f;
                sr = __builtin_fmaf(hm, vR[j], sr);
                sg = __builtin_fmaf(hm, vG[j], sg);
                sb = __builtin_fmaf(hm, vB[j], sb);
            }
        }
    }
    sr += __shfl_xor(sr, 32);
    sg += __shfl_xor(sg, 32);
    sb += __shfl_xor(sb, 32);

    if (half == 0) ss[w][cl] = make_float4(sr, sg, sb, 0.f);
    __syncthreads();

    float4 s0 = ss[0][cl], s1 = ss[1][cl], s2 = ss[2][cl], s3 = ss[3][cl];
    float fbc = (float)bc;
    float orv = (s0.x + s1.x + s2.x + s3.x) / fbc;
    float ogv = (s0.y + s1.y + s2.y + s3.y) / fbc;
    float obv = (s0.z + s1.z + s2.z + s3.z) / fbc;

    // ---- write: part p owns row p of the 8x8 block, 2x float4 per channel ----
    size_t base = (size_t)(oy * 8 + p) * Wd + (size_t)(ox * 8);
    float vals[3] = { orv, ogv, obv };
#pragma unroll
    for (int c = 0; c < 3; ++c) {
        float v = vals[c];
        float4 vv = make_float4(v, v, v, v);
        float* o = out + (size_t)c * HW + base;
        ((float4*)o)[0] = vv;
        ((float4*)o)[1] = vv;
    }
}

extern "C" void kernel_launch(void* const* d_in, const int* in_sizes, int n_in,
                              void* d_out, int out_size, void* d_ws, size_t ws_size,
                              hipStream_t stream) {
    const float* rgb = (const float*)d_in[0];
    float* out = (float*)d_out;
    dim3 block(256, 1, 1);                // 4 waves; wave = 32 cells x 2 parts
    dim3 grid(2048, 1, 1);                // 8 strips/cell-row x 256 rows (swizzled)
    hipLaunchKernelGGL(pixel_effect_kernel, grid, block, 0, stream, rgb, out);
}